// Round 13
// baseline (419.286 us; speedup 1.0000x reference)
//
#include <hip/hip_runtime.h>

#define B_ 8
#define T_ 4096
#define D_ 1024
#define H_ 8
#define HD_ 128
#define P_ 1024
#define OUT_ 1024
#define W_ 128
#define NC_ 64      // yacc chunks (chunk = 64 tokens)
#define CH_ 64
#define NPC_ 64     // d-chunks for pooled partials
#define PCH_ 16     // rows per pooled chunk

#define TRL_ 32     // rows per k_logits block

// K1: qp[h*D+d] = (1/sqrt(HD)) * sum_e w_kv[d][h*HD+e] * query[h][e]
__global__ void __launch_bounds__(256) k_qproj(const float* __restrict__ w_kv,
                                               const float* __restrict__ query,
                                               float* __restrict__ qp) {
  int d = blockIdx.x;   // 1024
  int t = threadIdx.x;  // 256, covers K-half row (1024 floats) as float4
  float4 wv = ((const float4*)(w_kv + (size_t)d * (2 * P_)))[t];
  float4 qv = ((const float4*)query)[t];  // query flat index == K-half column index
  float a = wv.x * qv.x + wv.y * qv.y + wv.z * qv.z + wv.w * qv.w;
#pragma unroll
  for (int off = 16; off; off >>= 1) a += __shfl_xor(a, off, 64);  // within 32-lane group
  if ((t & 31) == 0) {
    int h = t >> 5;
    qp[h * D_ + d] = a * 0.08838834764831845f;  // 1/sqrt(128)
  }
}

// K2 v9: logits[(b*H+h)*T + t] = dot(x[b,t,:], qp[h,:])
// 2 rows per 16-lane group; 4-slot register rotation keeps 8 x-loads in flight
// per wave (16 waves/CU x 8 x 16B = 2KB/CU -> HBM-saturating MLP).
__global__ void __launch_bounds__(256, 4) k_logits(const float* __restrict__ x,
                                                   const float* __restrict__ qp,
                                                   float* __restrict__ logits) {
  __shared__ float s_q[H_ * D_];        // 32 KB
  __shared__ float s_out[H_][TRL_ + 1]; // padded
  const int t = threadIdx.x;
  for (int i = t; i < H_ * D_ / 4; i += 256)
    ((float4*)s_q)[i] = ((const float4*)qp)[i];
  __syncthreads();

  const int w = t >> 6;        // wave 0..3
  const int l = t & 63;
  const int grp = l >> 4;      // 16-lane group; owns rows lrow0, lrow0+1
  const int c16 = l & 15;      // column slot (64 floats of D per k-step)
  const int R0 = blockIdx.x * TRL_;
  const bool b0 = (c16 & 1), b1 = (c16 & 2), b2 = (c16 & 4);
  const int hsel = (c16 & 1) * 4 + ((c16 >> 1) & 1) * 2 + ((c16 >> 2) & 1);

  const int lrow0 = w * 8 + grp * 2;   // 0..30
  const float4* xr0 = (const float4*)(x + ((size_t)(R0 + lrow0) << 10));
  const float4* xr1 = (const float4*)(x + ((size_t)(R0 + lrow0 + 1) << 10));

  float4 p40[H_], p41[H_];
#pragma unroll
  for (int h = 0; h < H_; ++h) {
    p40[h] = make_float4(0.f, 0.f, 0.f, 0.f);
    p41[h] = make_float4(0.f, 0.f, 0.f, 0.f);
  }
  // 4-slot rotation buffers: 8 float4 loads in flight per wave
  float4 bv0[4], bv1[4];
#pragma unroll
  for (int s = 0; s < 4; ++s) {
    bv0[s] = xr0[s * 16 + c16];
    bv1[s] = xr1[s * 16 + c16];
  }
#pragma unroll 1
  for (int kc4 = 0; kc4 < 4; ++kc4) {   // rolled outer: 4 kc per iter
#pragma unroll
    for (int s = 0; s < 4; ++s) {       // static slots
      const int kc = kc4 * 4 + s;
      float4 xc0 = bv0[s], xc1 = bv1[s];
      if (kc4 < 3) {                    // refill slot; stays in flight ~3 slots' compute
        bv0[s] = xr0[(kc + 4) * 16 + c16];
        bv1[s] = xr1[(kc + 4) * 16 + c16];
      }
      const float* qb = s_q + kc * 64 + c16 * 4;
#pragma unroll
      for (int h = 0; h < H_; ++h) {
        float4 qv = *(const float4*)(qb + h * D_);  // broadcast within 16-lane group
        p40[h].x += xc0.x * qv.x; p40[h].y += xc0.y * qv.y;
        p40[h].z += xc0.z * qv.z; p40[h].w += xc0.w * qv.w;
        p41[h].x += xc1.x * qv.x; p41[h].y += xc1.y * qv.y;
        p41[h].z += xc1.z * qv.z; p41[h].w += xc1.w * qv.w;
      }
    }
  }
#pragma unroll
  for (int r = 0; r < 2; ++r) {
    float p[H_];
#pragma unroll
    for (int h = 0; h < H_; ++h) {
      float4 q = r ? p41[h] : p40[h];
      p[h] = (q.x + q.y) + (q.z + q.w);
    }
    // split-butterfly over the 16-lane group: 8 shuffles per row
    float v0 = (b0 ? p[4] : p[0]) + __shfl_xor(b0 ? p[0] : p[4], 1, 64);
    float v1 = (b0 ? p[5] : p[1]) + __shfl_xor(b0 ? p[1] : p[5], 1, 64);
    float v2 = (b0 ? p[6] : p[2]) + __shfl_xor(b0 ? p[2] : p[6], 1, 64);
    float v3 = (b0 ? p[7] : p[3]) + __shfl_xor(b0 ? p[3] : p[7], 1, 64);
    float w0 = (b1 ? v2 : v0) + __shfl_xor(b1 ? v0 : v2, 2, 64);
    float w1 = (b1 ? v3 : v1) + __shfl_xor(b1 ? v1 : v3, 2, 64);
    float u = (b2 ? w1 : w0) + __shfl_xor(b2 ? w0 : w1, 4, 64);
    u += __shfl_xor(u, 8, 64);
    if (c16 < 8) s_out[hsel][lrow0 + r] = u;
  }
  __syncthreads();
  {  // coalesced write: 8 head-rows x 32 floats
    int hh = t >> 5, j = t & 31;
    int b = R0 >> 12, t0 = R0 & (T_ - 1);
    logits[(((size_t)(b * H_ + hh)) << 12) + t0 + j] = s_out[hh][j];
  }
}

// K4 (fused): window softmax stats + weights in LDS + yacc, 16-deep load pipe
// (8 waves/CU x 16 x 16B = 2KB/CU in flight).
// partial[c][b][h][d] = sum_{t in chunk c} weight[b,h,t] * x[b,t,d]
__global__ void __launch_bounds__(256, 4) k_yacc(const float* __restrict__ x,
                                                 const float* __restrict__ logits,
                                                 float* __restrict__ partial) {
  int c = blockIdx.x;              // NC_=64, chunk CH_=64
  int b = blockIdx.y;
  int t0 = c * CH_;
  int W0 = (t0 >> 5) - 1;          // first window needed (may be -1)
  __shared__ float sw[CH_][H_];    // [tt][h] -> per-tt weights as 2 broadcast float4
  __shared__ float sm[4][H_], srs[4][H_];
  int tid = threadIdx.x;
  if (tid < 3 * H_) {              // 24 threads: one (window, head) each
    int wi = tid >> 3, h = tid & 7;
    int w = W0 + wi;
    if (w >= 0 && w < W_) {
      const float* L = logits + (((size_t)(b * H_ + h)) << 12) + (w << 5);
      int cnt = min(64, T_ - (w << 5));  // window 127 has 32 valid entries
      float m = -1e30f;
#pragma unroll 8
      for (int i = 0; i < cnt; ++i) m = fmaxf(m, L[i]);
      float s = 0.f;
#pragma unroll 8
      for (int i = 0; i < cnt; ++i) s += __expf(L[i] - m);
      sm[wi][h] = m;
      srs[wi][h] = 1.0f / s;
    }
  }
  __syncthreads();
  const float invW = 1.0f / (float)W_;
  for (int i = tid; i < H_ * CH_; i += 256) {
    int h = i >> 6, tt = i & 63;
    int tg = t0 + tt;
    float l = logits[(((size_t)(b * H_ + h)) << 12) + tg];
    int w1 = tg >> 5;
    int rel = w1 - W0;             // 1 or 2
    float acc = __expf(l - sm[rel][h]) * srs[rel][h];
    if (w1 > 0) acc += __expf(l - sm[rel - 1][h]) * srs[rel - 1][h];
    sw[tt][h] = acc * invW;
  }
  __syncthreads();
  float4 acc[H_];
#pragma unroll
  for (int h = 0; h < H_; ++h) acc[h] = make_float4(0.f, 0.f, 0.f, 0.f);
  const float4* xb = (const float4*)(x + ((size_t)b * T_ + t0) * D_);
#pragma unroll 1
  for (int tt0 = 0; tt0 < CH_; tt0 += 16) {
    float4 xv[16];
#pragma unroll
    for (int j = 0; j < 16; ++j) xv[j] = xb[(tt0 + j) * (D_ / 4) + tid];  // 16 in flight
#pragma unroll
    for (int j = 0; j < 16; ++j) {
      float4 wa = *(const float4*)&sw[tt0 + j][0];  // broadcast b128
      float4 wb = *(const float4*)&sw[tt0 + j][4];
      acc[0].x += wa.x * xv[j].x; acc[0].y += wa.x * xv[j].y; acc[0].z += wa.x * xv[j].z; acc[0].w += wa.x * xv[j].w;
      acc[1].x += wa.y * xv[j].x; acc[1].y += wa.y * xv[j].y; acc[1].z += wa.y * xv[j].z; acc[1].w += wa.y * xv[j].w;
      acc[2].x += wa.z * xv[j].x; acc[2].y += wa.z * xv[j].y; acc[2].z += wa.z * xv[j].z; acc[2].w += wa.z * xv[j].w;
      acc[3].x += wa.w * xv[j].x; acc[3].y += wa.w * xv[j].y; acc[3].z += wa.w * xv[j].z; acc[3].w += wa.w * xv[j].w;
      acc[4].x += wb.x * xv[j].x; acc[4].y += wb.x * xv[j].y; acc[4].z += wb.x * xv[j].z; acc[4].w += wb.x * xv[j].w;
      acc[5].x += wb.y * xv[j].x; acc[5].y += wb.y * xv[j].y; acc[5].z += wb.y * xv[j].z; acc[5].w += wb.y * xv[j].w;
      acc[6].x += wb.z * xv[j].x; acc[6].y += wb.z * xv[j].y; acc[6].z += wb.z * xv[j].z; acc[6].w += wb.z * xv[j].w;
      acc[7].x += wb.w * xv[j].x; acc[7].y += wb.w * xv[j].y; acc[7].z += wb.w * xv[j].z; acc[7].w += wb.w * xv[j].w;
    }
  }
  float4* pp = (float4*)(partial + (((size_t)(c * B_ + b) * H_) << 10));
#pragma unroll
  for (int h = 0; h < H_; ++h) pp[h * (D_ / 4) + tid] = acc[h];
}

// K5: y[b*H+h][d] = sum_c partial[c][b][h][d]
__global__ void __launch_bounds__(256) k_reduce_y(const float* __restrict__ partial,
                                                  float* __restrict__ y) {
  int i = blockIdx.x * blockDim.x + threadIdx.x;  // over B*H*D/4 float4s
  float4 a = make_float4(0.f, 0.f, 0.f, 0.f);
  const float4* p = (const float4*)partial;
#pragma unroll 8
  for (int c = 0; c < NC_; ++c) {
    float4 v = p[(size_t)c * (B_ * H_ * D_ / 4) + i];
    a.x += v.x; a.y += v.y; a.z += v.z; a.w += v.w;
  }
  ((float4*)y)[i] = a;
}

// K6a: ppart[c][b][p] = sum_{d in chunk c} y[b,h(p),d] * w_kv[d][P+p]
__global__ void __launch_bounds__(256) k_pooled_part(const float* __restrict__ y,
                                                     const float* __restrict__ w_kv,
                                                     float* __restrict__ ppart) {
  int c = blockIdx.x;   // NPC_=64 chunks of PCH_=16 rows
  int d0 = c * PCH_;
  int t = threadIdx.x;  // owns columns 4t..4t+3 of P
  int h = t >> 5;       // head of those columns
  __shared__ float sy[PCH_][B_ * H_];  // sy[dd][b*8+h]
  for (int i = t; i < PCH_ * B_ * H_; i += 256) {
    int dd = i >> 6, bh = i & 63;
    sy[dd][bh] = y[((size_t)bh << 10) + d0 + dd];
  }
  __syncthreads();
  float4 acc[B_];
#pragma unroll
  for (int b = 0; b < B_; ++b) acc[b] = make_float4(0.f, 0.f, 0.f, 0.f);
#pragma unroll
  for (int dd = 0; dd < PCH_; ++dd) {
    float4 wv = ((const float4*)(w_kv + (size_t)(d0 + dd) * (2 * P_) + P_))[t];
#pragma unroll
    for (int b = 0; b < B_; ++b) {
      float yv = sy[dd][b * H_ + h];
      acc[b].x += yv * wv.x; acc[b].y += yv * wv.y;
      acc[b].z += yv * wv.z; acc[b].w += yv * wv.w;
    }
  }
#pragma unroll
  for (int b = 0; b < B_; ++b)
    ((float4*)(ppart + (((size_t)c * B_ + b) << 10)))[t] = acc[b];
}

// K6b: pooled[b][p] = sum_c ppart[c][b][p]
__global__ void __launch_bounds__(256) k_reduce_pooled(const float* __restrict__ ppart,
                                                       float* __restrict__ pooled) {
  int i = blockIdx.x * 256 + threadIdx.x;  // 2048 float4s over (b,p)
  int b = i >> 8, p4 = i & 255;
  float4 a = make_float4(0.f, 0.f, 0.f, 0.f);
  const float4* p = (const float4*)ppart;
#pragma unroll 8
  for (int c = 0; c < NPC_; ++c) {
    float4 v = p[((c * B_ + b) << 8) + p4];
    a.x += v.x; a.y += v.y; a.z += v.z; a.w += v.w;
  }
  ((float4*)pooled)[i] = a;
}

// K7: out[b][o] = sum_p pooled[b][p] * w_out_w[o][p] + w_out_b[o]  (wave per o)
__global__ void __launch_bounds__(256) k_out(const float* __restrict__ pooled,
                                             const float* __restrict__ w_out_w,
                                             const float* __restrict__ w_out_b,
                                             float* __restrict__ out) {
  int wid = threadIdx.x >> 6, lane = threadIdx.x & 63;
  int o = blockIdx.x * 4 + wid;  // 1024 outputs
  const float4* wr = (const float4*)(w_out_w + (size_t)o * P_);
  float4 wv[4];
#pragma unroll
  for (int j = 0; j < 4; ++j) wv[j] = wr[lane + 64 * j];
  float res[B_];
#pragma unroll
  for (int b = 0; b < B_; ++b) {
    const float4* pb = (const float4*)(pooled + b * P_);
    float a = 0.f;
#pragma unroll
    for (int j = 0; j < 4; ++j) {
      float4 pv = pb[lane + 64 * j];
      a += wv[j].x * pv.x + wv[j].y * pv.y + wv[j].z * pv.z + wv[j].w * pv.w;
    }
#pragma unroll
    for (int off = 32; off; off >>= 1) a += __shfl_down(a, off, 64);
    res[b] = a;
  }
  if (lane == 0) {
    float bias = w_out_b[o];
#pragma unroll
    for (int b = 0; b < B_; ++b) out[b * OUT_ + o] = res[b] + bias;
  }
}

extern "C" void kernel_launch(void* const* d_in, const int* in_sizes, int n_in,
                              void* d_out, int out_size, void* d_ws, size_t ws_size,
                              hipStream_t stream) {
  const float* x       = (const float*)d_in[0];  // (B,T,D)
  const float* w_kv    = (const float*)d_in[1];  // (D, 2P)
  const float* query   = (const float*)d_in[2];  // (H, HD)
  const float* w_out_w = (const float*)d_in[3];  // (OUT, P)
  const float* w_out_b = (const float*)d_in[4];  // (OUT,)
  float* out = (float*)d_out;                    // (B, OUT)

  float* ws = (float*)d_ws;
  float* qp      = ws;                                    // H*D     = 8192
  float* logits  = qp + H_ * D_;                          // B*H*T   = 262144
  float* partial = logits + B_ * H_ * T_;                 // NC*B*H*D = 4194304
  float* y       = partial + (size_t)NC_ * B_ * H_ * D_;  // B*H*D   = 65536
  float* pooled  = y + B_ * H_ * D_;                      // B*P     = 8192
  // ppart reuses the yacc partial buffer (free after k_reduce_y): NPC*B*P = 524288 floats
  float* ppart   = partial;

  k_qproj<<<D_, 256, 0, stream>>>(w_kv, query, qp);
  k_logits<<<B_ * T_ / TRL_, 256, 0, stream>>>(x, qp, logits);
  k_yacc<<<dim3(NC_, B_), 256, 0, stream>>>(x, logits, partial);
  k_reduce_y<<<(B_ * H_ * D_ / 4) / 256, 256, 0, stream>>>(partial, y);
  k_pooled_part<<<NPC_, 256, 0, stream>>>(y, w_kv, ppart);
  k_reduce_pooled<<<(B_ * P_ / 4) / 256, 256, 0, stream>>>(ppart, pooled);
  k_out<<<OUT_ / 4, 256, 0, stream>>>(pooled, w_out_w, w_out_b, out);
}

// Round 14
// 308.641 us; speedup vs baseline: 1.3585x; 1.3585x over previous
//
#include <hip/hip_runtime.h>

#define B_ 8
#define T_ 4096
#define D_ 1024
#define H_ 8
#define HD_ 128
#define P_ 1024
#define OUT_ 1024
#define W_ 128
#define NC_ 64      // yacc chunks (chunk = 64 tokens)
#define CH_ 64
#define NPC_ 64     // d-chunks for pooled partials
#define PCH_ 16     // rows per pooled chunk

#define TRL_ 32     // rows per k_logits block

// K1: qp[h*D+d] = (1/sqrt(HD)) * sum_e w_kv[d][h*HD+e] * query[h][e]
__global__ void __launch_bounds__(256) k_qproj(const float* __restrict__ w_kv,
                                               const float* __restrict__ query,
                                               float* __restrict__ qp) {
  int d = blockIdx.x;   // 1024
  int t = threadIdx.x;  // 256, covers K-half row (1024 floats) as float4
  float4 wv = ((const float4*)(w_kv + (size_t)d * (2 * P_)))[t];
  float4 qv = ((const float4*)query)[t];  // query flat index == K-half column index
  float a = wv.x * qv.x + wv.y * qv.y + wv.z * qv.z + wv.w * qv.w;
#pragma unroll
  for (int off = 16; off; off >>= 1) a += __shfl_xor(a, off, 64);  // within 32-lane group
  if ((t & 31) == 0) {
    int h = t >> 5;
    qp[h * D_ + d] = a * 0.08838834764831845f;  // 1/sqrt(128)
  }
}

// K2 v10: logits[(b*H+h)*T + t] = dot(x[b,t,:], qp[h,:])
// 2 rows per 16-lane group; depth-4 software pipeline with 8 NAMED float4
// buffers (no arrays -> no scratch, rule #20) and UNCONDITIONAL refill in the
// steady-state loop (predicated refill in v9 doubled live ranges and spilled).
__global__ void __launch_bounds__(256, 4) k_logits(const float* __restrict__ x,
                                                   const float* __restrict__ qp,
                                                   float* __restrict__ logits) {
  __shared__ float s_q[H_ * D_];        // 32 KB
  __shared__ float s_out[H_][TRL_ + 1]; // padded
  const int t = threadIdx.x;
  for (int i = t; i < H_ * D_ / 4; i += 256)
    ((float4*)s_q)[i] = ((const float4*)qp)[i];
  __syncthreads();

  const int w = t >> 6;        // wave 0..3
  const int l = t & 63;
  const int grp = l >> 4;      // 16-lane group; owns rows lrow0, lrow0+1
  const int c16 = l & 15;      // column slot (64 floats of D per k-step)
  const int R0 = blockIdx.x * TRL_;
  const bool bb0 = (c16 & 1), bb1 = (c16 & 2), bb2 = (c16 & 4);
  const int hsel = (c16 & 1) * 4 + ((c16 >> 1) & 1) * 2 + ((c16 >> 2) & 1);

  const int lrow0 = w * 8 + grp * 2;   // 0..30
  const float4* xr0 = (const float4*)(x + ((size_t)(R0 + lrow0) << 10));
  const float4* xr1 = (const float4*)(x + ((size_t)(R0 + lrow0 + 1) << 10));

  float4 p40[H_], p41[H_];
#pragma unroll
  for (int h = 0; h < H_; ++h) {
    p40[h] = make_float4(0.f, 0.f, 0.f, 0.f);
    p41[h] = make_float4(0.f, 0.f, 0.f, 0.f);
  }

  auto fma8 = [&](const float4& xc0, const float4& xc1, int kc) {
    const float* qb = s_q + kc * 64 + c16 * 4;
#pragma unroll
    for (int h = 0; h < H_; ++h) {
      float4 qv = *(const float4*)(qb + h * D_);  // broadcast within 16-lane group
      p40[h].x += xc0.x * qv.x; p40[h].y += xc0.y * qv.y;
      p40[h].z += xc0.z * qv.z; p40[h].w += xc0.w * qv.w;
      p41[h].x += xc1.x * qv.x; p41[h].y += xc1.y * qv.y;
      p41[h].z += xc1.z * qv.z; p41[h].w += xc1.w * qv.w;
    }
  };

  // 4 named slots x 2 rows = 8 float4 buffers, depth-4 pipeline
  float4 a0 = xr0[0 * 16 + c16], a1 = xr1[0 * 16 + c16];
  float4 b0 = xr0[1 * 16 + c16], b1 = xr1[1 * 16 + c16];
  float4 c0 = xr0[2 * 16 + c16], c1 = xr1[2 * 16 + c16];
  float4 d0 = xr0[3 * 16 + c16], d1 = xr1[3 * 16 + c16];
#pragma unroll 1
  for (int kc4 = 0; kc4 < 3; ++kc4) {   // steady state: unconditional refill
    const int kc = kc4 * 4;
    fma8(a0, a1, kc);
    a0 = xr0[(kc + 4) * 16 + c16]; a1 = xr1[(kc + 4) * 16 + c16];
    fma8(b0, b1, kc + 1);
    b0 = xr0[(kc + 5) * 16 + c16]; b1 = xr1[(kc + 5) * 16 + c16];
    fma8(c0, c1, kc + 2);
    c0 = xr0[(kc + 6) * 16 + c16]; c1 = xr1[(kc + 6) * 16 + c16];
    fma8(d0, d1, kc + 3);
    d0 = xr0[(kc + 7) * 16 + c16]; d1 = xr1[(kc + 7) * 16 + c16];
  }
  // peeled epilogue: kc = 12..15, no refill
  fma8(a0, a1, 12);
  fma8(b0, b1, 13);
  fma8(c0, c1, 14);
  fma8(d0, d1, 15);

#pragma unroll
  for (int r = 0; r < 2; ++r) {
    float p[H_];
#pragma unroll
    for (int h = 0; h < H_; ++h) {
      float4 q = r ? p41[h] : p40[h];
      p[h] = (q.x + q.y) + (q.z + q.w);
    }
    // split-butterfly over the 16-lane group: 8 shuffles per row
    float v0 = (bb0 ? p[4] : p[0]) + __shfl_xor(bb0 ? p[0] : p[4], 1, 64);
    float v1 = (bb0 ? p[5] : p[1]) + __shfl_xor(bb0 ? p[1] : p[5], 1, 64);
    float v2 = (bb0 ? p[6] : p[2]) + __shfl_xor(bb0 ? p[2] : p[6], 1, 64);
    float v3 = (bb0 ? p[7] : p[3]) + __shfl_xor(bb0 ? p[3] : p[7], 1, 64);
    float w0 = (bb1 ? v2 : v0) + __shfl_xor(bb1 ? v0 : v2, 2, 64);
    float w1 = (bb1 ? v3 : v1) + __shfl_xor(bb1 ? v1 : v3, 2, 64);
    float u = (bb2 ? w1 : w0) + __shfl_xor(bb2 ? w0 : w1, 4, 64);
    u += __shfl_xor(u, 8, 64);
    if (c16 < 8) s_out[hsel][lrow0 + r] = u;
  }
  __syncthreads();
  {  // coalesced write: 8 head-rows x 32 floats
    int hh = t >> 5, j = t & 31;
    int b = R0 >> 12, t0 = R0 & (T_ - 1);
    logits[(((size_t)(b * H_ + hh)) << 12) + t0 + j] = s_out[hh][j];
  }
}

// K4 (fused): per-block window softmax stats + weights in LDS + yacc, 8-deep load pipe.
// partial[c][b][h][d] = sum_{t in chunk c} weight[b,h,t] * x[b,t,d]
__global__ void __launch_bounds__(256) k_yacc(const float* __restrict__ x,
                                              const float* __restrict__ logits,
                                              float* __restrict__ partial) {
  int c = blockIdx.x;              // NC_=64, chunk CH_=64
  int b = blockIdx.y;
  int t0 = c * CH_;
  int W0 = (t0 >> 5) - 1;          // first window needed (may be -1)
  __shared__ float sw[CH_][H_];    // [tt][h] -> per-tt weights as 2 broadcast float4
  __shared__ float sm[4][H_], srs[4][H_];
  int tid = threadIdx.x;
  if (tid < 3 * H_) {              // 24 threads: one (window, head) each
    int wi = tid >> 3, h = tid & 7;
    int w = W0 + wi;
    if (w >= 0 && w < W_) {
      const float* L = logits + (((size_t)(b * H_ + h)) << 12) + (w << 5);
      int cnt = min(64, T_ - (w << 5));  // window 127 has 32 valid entries
      float m = -1e30f;
#pragma unroll 8
      for (int i = 0; i < cnt; ++i) m = fmaxf(m, L[i]);
      float s = 0.f;
#pragma unroll 8
      for (int i = 0; i < cnt; ++i) s += __expf(L[i] - m);
      sm[wi][h] = m;
      srs[wi][h] = 1.0f / s;
    }
  }
  __syncthreads();
  const float invW = 1.0f / (float)W_;
  for (int i = tid; i < H_ * CH_; i += 256) {
    int h = i >> 6, tt = i & 63;
    int tg = t0 + tt;
    float l = logits[(((size_t)(b * H_ + h)) << 12) + tg];
    int w1 = tg >> 5;
    int rel = w1 - W0;             // 1 or 2
    float acc = __expf(l - sm[rel][h]) * srs[rel][h];
    if (w1 > 0) acc += __expf(l - sm[rel - 1][h]) * srs[rel - 1][h];
    sw[tt][h] = acc * invW;
  }
  __syncthreads();
  float4 acc[H_];
#pragma unroll
  for (int h = 0; h < H_; ++h) acc[h] = make_float4(0.f, 0.f, 0.f, 0.f);
  const float4* xb = (const float4*)(x + ((size_t)b * T_ + t0) * D_);
  for (int tt0 = 0; tt0 < CH_; tt0 += 8) {
    float4 xv[8];
#pragma unroll
    for (int j = 0; j < 8; ++j) xv[j] = xb[(tt0 + j) * (D_ / 4) + tid];  // 8 loads in flight
#pragma unroll
    for (int j = 0; j < 8; ++j) {
      float4 wa = *(const float4*)&sw[tt0 + j][0];  // broadcast b128
      float4 wb = *(const float4*)&sw[tt0 + j][4];
      acc[0].x += wa.x * xv[j].x; acc[0].y += wa.x * xv[j].y; acc[0].z += wa.x * xv[j].z; acc[0].w += wa.x * xv[j].w;
      acc[1].x += wa.y * xv[j].x; acc[1].y += wa.y * xv[j].y; acc[1].z += wa.y * xv[j].z; acc[1].w += wa.y * xv[j].w;
      acc[2].x += wa.z * xv[j].x; acc[2].y += wa.z * xv[j].y; acc[2].z += wa.z * xv[j].z; acc[2].w += wa.z * xv[j].w;
      acc[3].x += wa.w * xv[j].x; acc[3].y += wa.w * xv[j].y; acc[3].z += wa.w * xv[j].z; acc[3].w += wa.w * xv[j].w;
      acc[4].x += wb.x * xv[j].x; acc[4].y += wb.x * xv[j].y; acc[4].z += wb.x * xv[j].z; acc[4].w += wb.x * xv[j].w;
      acc[5].x += wb.y * xv[j].x; acc[5].y += wb.y * xv[j].y; acc[5].z += wb.y * xv[j].z; acc[5].w += wb.y * xv[j].w;
      acc[6].x += wb.z * xv[j].x; acc[6].y += wb.z * xv[j].y; acc[6].z += wb.z * xv[j].z; acc[6].w += wb.z * xv[j].w;
      acc[7].x += wb.w * xv[j].x; acc[7].y += wb.w * xv[j].y; acc[7].z += wb.w * xv[j].z; acc[7].w += wb.w * xv[j].w;
    }
  }
  float4* pp = (float4*)(partial + (((size_t)(c * B_ + b) * H_) << 10));
#pragma unroll
  for (int h = 0; h < H_; ++h) pp[h * (D_ / 4) + tid] = acc[h];
}

// K5: y[b*H+h][d] = sum_c partial[c][b][h][d]
__global__ void __launch_bounds__(256) k_reduce_y(const float* __restrict__ partial,
                                                  float* __restrict__ y) {
  int i = blockIdx.x * blockDim.x + threadIdx.x;  // over B*H*D/4 float4s
  float4 a = make_float4(0.f, 0.f, 0.f, 0.f);
  const float4* p = (const float4*)partial;
#pragma unroll 8
  for (int c = 0; c < NC_; ++c) {
    float4 v = p[(size_t)c * (B_ * H_ * D_ / 4) + i];
    a.x += v.x; a.y += v.y; a.z += v.z; a.w += v.w;
  }
  ((float4*)y)[i] = a;
}

// K6a: ppart[c][b][p] = sum_{d in chunk c} y[b,h(p),d] * w_kv[d][P+p]
__global__ void __launch_bounds__(256) k_pooled_part(const float* __restrict__ y,
                                                     const float* __restrict__ w_kv,
                                                     float* __restrict__ ppart) {
  int c = blockIdx.x;   // NPC_=64 chunks of PCH_=16 rows
  int d0 = c * PCH_;
  int t = threadIdx.x;  // owns columns 4t..4t+3 of P
  int h = t >> 5;       // head of those columns
  __shared__ float sy[PCH_][B_ * H_];  // sy[dd][b*8+h]
  for (int i = t; i < PCH_ * B_ * H_; i += 256) {
    int dd = i >> 6, bh = i & 63;
    sy[dd][bh] = y[((size_t)bh << 10) + d0 + dd];
  }
  __syncthreads();
  float4 acc[B_];
#pragma unroll
  for (int b = 0; b < B_; ++b) acc[b] = make_float4(0.f, 0.f, 0.f, 0.f);
#pragma unroll
  for (int dd = 0; dd < PCH_; ++dd) {
    float4 wv = ((const float4*)(w_kv + (size_t)(d0 + dd) * (2 * P_) + P_))[t];
#pragma unroll
    for (int b = 0; b < B_; ++b) {
      float yv = sy[dd][b * H_ + h];
      acc[b].x += yv * wv.x; acc[b].y += yv * wv.y;
      acc[b].z += yv * wv.z; acc[b].w += yv * wv.w;
    }
  }
#pragma unroll
  for (int b = 0; b < B_; ++b)
    ((float4*)(ppart + (((size_t)c * B_ + b) << 10)))[t] = acc[b];
}

// K6b: pooled[b][p] = sum_c ppart[c][b][p]
__global__ void __launch_bounds__(256) k_reduce_pooled(const float* __restrict__ ppart,
                                                       float* __restrict__ pooled) {
  int i = blockIdx.x * 256 + threadIdx.x;  // 2048 float4s over (b,p)
  int b = i >> 8, p4 = i & 255;
  float4 a = make_float4(0.f, 0.f, 0.f, 0.f);
  const float4* p = (const float4*)ppart;
#pragma unroll 8
  for (int c = 0; c < NPC_; ++c) {
    float4 v = p[((c * B_ + b) << 8) + p4];
    a.x += v.x; a.y += v.y; a.z += v.z; a.w += v.w;
  }
  ((float4*)pooled)[i] = a;
}

// K7: out[b][o] = sum_p pooled[b][p] * w_out_w[o][p] + w_out_b[o]  (wave per o)
__global__ void __launch_bounds__(256) k_out(const float* __restrict__ pooled,
                                             const float* __restrict__ w_out_w,
                                             const float* __restrict__ w_out_b,
                                             float* __restrict__ out) {
  int wid = threadIdx.x >> 6, lane = threadIdx.x & 63;
  int o = blockIdx.x * 4 + wid;  // 1024 outputs
  const float4* wr = (const float4*)(w_out_w + (size_t)o * P_);
  float4 wv[4];
#pragma unroll
  for (int j = 0; j < 4; ++j) wv[j] = wr[lane + 64 * j];
  float res[B_];
#pragma unroll
  for (int b = 0; b < B_; ++b) {
    const float4* pb = (const float4*)(pooled + b * P_);
    float a = 0.f;
#pragma unroll
    for (int j = 0; j < 4; ++j) {
      float4 pv = pb[lane + 64 * j];
      a += wv[j].x * pv.x + wv[j].y * pv.y + wv[j].z * pv.z + wv[j].w * pv.w;
    }
#pragma unroll
    for (int off = 32; off; off >>= 1) a += __shfl_down(a, off, 64);
    res[b] = a;
  }
  if (lane == 0) {
    float bias = w_out_b[o];
#pragma unroll
    for (int b = 0; b < B_; ++b) out[b * OUT_ + o] = res[b] + bias;
  }
}

extern "C" void kernel_launch(void* const* d_in, const int* in_sizes, int n_in,
                              void* d_out, int out_size, void* d_ws, size_t ws_size,
                              hipStream_t stream) {
  const float* x       = (const float*)d_in[0];  // (B,T,D)
  const float* w_kv    = (const float*)d_in[1];  // (D, 2P)
  const float* query   = (const float*)d_in[2];  // (H, HD)
  const float* w_out_w = (const float*)d_in[3];  // (OUT, P)
  const float* w_out_b = (const float*)d_in[4];  // (OUT,)
  float* out = (float*)d_out;                    // (B, OUT)

  float* ws = (float*)d_ws;
  float* qp      = ws;                                    // H*D     = 8192
  float* logits  = qp + H_ * D_;                          // B*H*T   = 262144
  float* partial = logits + B_ * H_ * T_;                 // NC*B*H*D = 4194304
  float* y       = partial + (size_t)NC_ * B_ * H_ * D_;  // B*H*D   = 65536
  float* pooled  = y + B_ * H_ * D_;                      // B*P     = 8192
  // ppart reuses the yacc partial buffer (free after k_reduce_y): NPC*B*P = 524288 floats
  float* ppart   = partial;

  k_qproj<<<D_, 256, 0, stream>>>(w_kv, query, qp);
  k_logits<<<B_ * T_ / TRL_, 256, 0, stream>>>(x, qp, logits);
  k_yacc<<<dim3(NC_, B_), 256, 0, stream>>>(x, logits, partial);
  k_reduce_y<<<(B_ * H_ * D_ / 4) / 256, 256, 0, stream>>>(partial, y);
  k_pooled_part<<<NPC_, 256, 0, stream>>>(y, w_kv, ppart);
  k_reduce_pooled<<<(B_ * P_ / 4) / 256, 256, 0, stream>>>(ppart, pooled);
  k_out<<<OUT_ / 4, 256, 0, stream>>>(pooled, w_out_w, w_out_b, out);
}

// Round 15
// 250.011 us; speedup vs baseline: 1.6771x; 1.2345x over previous
//
#include <hip/hip_runtime.h>

#define B_ 8
#define T_ 4096
#define D_ 1024
#define H_ 8
#define HD_ 128
#define P_ 1024
#define OUT_ 1024
#define W_ 128
#define NC_ 64      // yacc chunks (chunk = 64 tokens)
#define CH_ 64
#define NPC_ 64     // d-chunks for pooled partials
#define PCH_ 16     // rows per pooled chunk

#define TRL_ 32     // rows per k_logits block

// K1: qp[h*D+d] = (1/sqrt(HD)) * sum_e w_kv[d][h*HD+e] * query[h][e]
__global__ void __launch_bounds__(256) k_qproj(const float* __restrict__ w_kv,
                                               const float* __restrict__ query,
                                               float* __restrict__ qp) {
  int d = blockIdx.x;   // 1024
  int t = threadIdx.x;  // 256, covers K-half row (1024 floats) as float4
  float4 wv = ((const float4*)(w_kv + (size_t)d * (2 * P_)))[t];
  float4 qv = ((const float4*)query)[t];  // query flat index == K-half column index
  float a = wv.x * qv.x + wv.y * qv.y + wv.z * qv.z + wv.w * qv.w;
#pragma unroll
  for (int off = 16; off; off >>= 1) a += __shfl_xor(a, off, 64);  // within 32-lane group
  if ((t & 31) == 0) {
    int h = t >> 5;
    qp[h * D_ + d] = a * 0.08838834764831845f;  // 1/sqrt(128)
  }
}

// K2 v11: partial logits over a D-half: l{A,B}[(b*H+h)*T + t] = dot(x[b,t,half], qp[h,half])
// grid 2048 = 1024 row-tiles x 2 halves -> 8 blocks/CU; s_q 16KB; float2 accs (32 VGPR);
// 2-slot named-buffer rotation = 4 loads in flight/wave; NO launch_bounds cap (spill lesson).
__global__ void __launch_bounds__(256) k_logits(const float* __restrict__ x,
                                                const float* __restrict__ qp,
                                                float* __restrict__ lA,
                                                float* __restrict__ lB) {
  __shared__ float s_q[H_ * (D_ / 2)];   // 16 KB
  __shared__ float s_out[H_][TRL_ + 1];
  const int t = threadIdx.x;
  const int half = blockIdx.x & 1;
  const int rt = blockIdx.x >> 1;
  {
    const float4* qp4 = (const float4*)qp;
#pragma unroll
    for (int q = 0; q < 4; ++q) {
      int i = t + 256 * q;               // 0..1023 float4s of the q-half
      int h = i >> 7, j4 = i & 127;
      ((float4*)s_q)[i] = qp4[h * 256 + half * 128 + j4];
    }
  }
  __syncthreads();

  const int w = t >> 6, l = t & 63;
  const int grp = l >> 4;      // 16-lane group; owns rows lrow0, lrow0+1
  const int c16 = l & 15;
  const int R0 = rt * TRL_;
  const bool bb0 = (c16 & 1), bb1 = (c16 & 2), bb2 = (c16 & 4);
  const int hsel = (c16 & 1) * 4 + ((c16 >> 1) & 1) * 2 + ((c16 >> 2) & 1);
  const int lrow0 = w * 8 + grp * 2;     // 0..30

  const float4* xr0 = (const float4*)x + (R0 + lrow0) * 256 + half * 128;
  const float4* xr1 = xr0 + 256;

  float2 p20[H_], p21[H_];
#pragma unroll
  for (int h = 0; h < H_; ++h) {
    p20[h] = make_float2(0.f, 0.f);
    p21[h] = make_float2(0.f, 0.f);
  }

  auto fma8 = [&](const float4 xc0, const float4 xc1, int kk) {
    const float* qb = s_q + kk * 64 + c16 * 4;
#pragma unroll
    for (int h = 0; h < H_; ++h) {
      float4 qv = *(const float4*)(qb + h * (D_ / 2));  // broadcast in 16-lane group
      p20[h].x = fmaf(xc0.x, qv.x, p20[h].x); p20[h].x = fmaf(xc0.z, qv.z, p20[h].x);
      p20[h].y = fmaf(xc0.y, qv.y, p20[h].y); p20[h].y = fmaf(xc0.w, qv.w, p20[h].y);
      p21[h].x = fmaf(xc1.x, qv.x, p21[h].x); p21[h].x = fmaf(xc1.z, qv.z, p21[h].x);
      p21[h].y = fmaf(xc1.y, qv.y, p21[h].y); p21[h].y = fmaf(xc1.w, qv.w, p21[h].y);
    }
  };

  // 2 named slots x 2 rows: 4 loads in flight; unconditional refill; peeled tail
  float4 A0 = xr0[c16],      A1 = xr1[c16];
  float4 B0 = xr0[16 + c16], B1 = xr1[16 + c16];
#pragma unroll 1
  for (int j = 0; j < 3; ++j) {          // kk = 2j, 2j+1 ; refill -> 2j+2, 2j+3
    float4 tA0 = A0, tA1 = A1;
    A0 = xr0[(2 * j + 2) * 16 + c16]; A1 = xr1[(2 * j + 2) * 16 + c16];
    fma8(tA0, tA1, 2 * j);
    float4 tB0 = B0, tB1 = B1;
    B0 = xr0[(2 * j + 3) * 16 + c16]; B1 = xr1[(2 * j + 3) * 16 + c16];
    fma8(tB0, tB1, 2 * j + 1);
  }
  fma8(A0, A1, 6);
  fma8(B0, B1, 7);

#pragma unroll
  for (int r = 0; r < 2; ++r) {
    float p[H_];
#pragma unroll
    for (int h = 0; h < H_; ++h) {
      float2 q = r ? p21[h] : p20[h];
      p[h] = q.x + q.y;
    }
    // split-butterfly over the 16-lane group: 8 shuffles per row
    float v0 = (bb0 ? p[4] : p[0]) + __shfl_xor(bb0 ? p[0] : p[4], 1, 64);
    float v1 = (bb0 ? p[5] : p[1]) + __shfl_xor(bb0 ? p[1] : p[5], 1, 64);
    float v2 = (bb0 ? p[6] : p[2]) + __shfl_xor(bb0 ? p[2] : p[6], 1, 64);
    float v3 = (bb0 ? p[7] : p[3]) + __shfl_xor(bb0 ? p[3] : p[7], 1, 64);
    float w0 = (bb1 ? v2 : v0) + __shfl_xor(bb1 ? v0 : v2, 2, 64);
    float w1 = (bb1 ? v3 : v1) + __shfl_xor(bb1 ? v1 : v3, 2, 64);
    float u = (bb2 ? w1 : w0) + __shfl_xor(bb2 ? w0 : w1, 4, 64);
    u += __shfl_xor(u, 8, 64);
    if (c16 < 8) s_out[hsel][lrow0 + r] = u;
  }
  __syncthreads();
  {  // coalesced write: 8 head-rows x 32 floats into this half's partial buffer
    float* out = half ? lB : lA;
    int hh = t >> 5, j = t & 31;
    int b = R0 >> 12, t0 = R0 & (T_ - 1);
    out[(((size_t)(b * H_ + hh)) << 12) + t0 + j] = s_out[hh][j];
  }
}

// K4 (fused): window softmax stats + weights in LDS + yacc, 8-deep load pipe.
// logits = lA + lB (summed at read). partial[c][b][h][d] = sum_t w[b,h,t] * x[b,t,d]
__global__ void __launch_bounds__(256) k_yacc(const float* __restrict__ x,
                                              const float* __restrict__ lA,
                                              const float* __restrict__ lB,
                                              float* __restrict__ partial) {
  int c = blockIdx.x;              // NC_=64, chunk CH_=64
  int b = blockIdx.y;
  int t0 = c * CH_;
  int W0 = (t0 >> 5) - 1;          // first window needed (may be -1)
  __shared__ float sw[CH_][H_];
  __shared__ float sm[4][H_], srs[4][H_];
  int tid = threadIdx.x;
  if (tid < 3 * H_) {              // 24 threads: one (window, head) each
    int wi = tid >> 3, h = tid & 7;
    int w = W0 + wi;
    if (w >= 0 && w < W_) {
      size_t base = (((size_t)(b * H_ + h)) << 12) + (w << 5);
      const float* LAp = lA + base;
      const float* LBp = lB + base;
      int cnt = min(64, T_ - (w << 5));  // window 127 has 32 valid entries
      float m = -1e30f;
#pragma unroll 8
      for (int i = 0; i < cnt; ++i) m = fmaxf(m, LAp[i] + LBp[i]);
      float s = 0.f;
#pragma unroll 8
      for (int i = 0; i < cnt; ++i) s += __expf(LAp[i] + LBp[i] - m);
      sm[wi][h] = m;
      srs[wi][h] = 1.0f / s;
    }
  }
  __syncthreads();
  const float invW = 1.0f / (float)W_;
  for (int i = tid; i < H_ * CH_; i += 256) {
    int h = i >> 6, tt = i & 63;
    int tg = t0 + tt;
    size_t idx = (((size_t)(b * H_ + h)) << 12) + tg;
    float l = lA[idx] + lB[idx];
    int w1 = tg >> 5;
    int rel = w1 - W0;             // 1 or 2
    float acc = __expf(l - sm[rel][h]) * srs[rel][h];
    if (w1 > 0) acc += __expf(l - sm[rel - 1][h]) * srs[rel - 1][h];
    sw[tt][h] = acc * invW;
  }
  __syncthreads();
  float4 acc[H_];
#pragma unroll
  for (int h = 0; h < H_; ++h) acc[h] = make_float4(0.f, 0.f, 0.f, 0.f);
  const float4* xb = (const float4*)(x + ((size_t)b * T_ + t0) * D_);
  for (int tt0 = 0; tt0 < CH_; tt0 += 8) {
    float4 xv[8];
#pragma unroll
    for (int j = 0; j < 8; ++j) xv[j] = xb[(tt0 + j) * (D_ / 4) + tid];  // 8 loads in flight
#pragma unroll
    for (int j = 0; j < 8; ++j) {
      float4 wa = *(const float4*)&sw[tt0 + j][0];  // broadcast b128
      float4 wb = *(const float4*)&sw[tt0 + j][4];
      acc[0].x += wa.x * xv[j].x; acc[0].y += wa.x * xv[j].y; acc[0].z += wa.x * xv[j].z; acc[0].w += wa.x * xv[j].w;
      acc[1].x += wa.y * xv[j].x; acc[1].y += wa.y * xv[j].y; acc[1].z += wa.y * xv[j].z; acc[1].w += wa.y * xv[j].w;
      acc[2].x += wa.z * xv[j].x; acc[2].y += wa.z * xv[j].y; acc[2].z += wa.z * xv[j].z; acc[2].w += wa.z * xv[j].w;
      acc[3].x += wa.w * xv[j].x; acc[3].y += wa.w * xv[j].y; acc[3].z += wa.w * xv[j].z; acc[3].w += wa.w * xv[j].w;
      acc[4].x += wb.x * xv[j].x; acc[4].y += wb.x * xv[j].y; acc[4].z += wb.x * xv[j].z; acc[4].w += wb.x * xv[j].w;
      acc[5].x += wb.y * xv[j].x; acc[5].y += wb.y * xv[j].y; acc[5].z += wb.y * xv[j].z; acc[5].w += wb.y * xv[j].w;
      acc[6].x += wb.z * xv[j].x; acc[6].y += wb.z * xv[j].y; acc[6].z += wb.z * xv[j].z; acc[6].w += wb.z * xv[j].w;
      acc[7].x += wb.w * xv[j].x; acc[7].y += wb.w * xv[j].y; acc[7].z += wb.w * xv[j].z; acc[7].w += wb.w * xv[j].w;
    }
  }
  float4* pp = (float4*)(partial + (((size_t)(c * B_ + b) * H_) << 10));
#pragma unroll
  for (int h = 0; h < H_; ++h) pp[h * (D_ / 4) + tid] = acc[h];
}

// K5: y[b*H+h][d] = sum_c partial[c][b][h][d]
__global__ void __launch_bounds__(256) k_reduce_y(const float* __restrict__ partial,
                                                  float* __restrict__ y) {
  int i = blockIdx.x * blockDim.x + threadIdx.x;  // over B*H*D/4 float4s
  float4 a = make_float4(0.f, 0.f, 0.f, 0.f);
  const float4* p = (const float4*)partial;
#pragma unroll 8
  for (int c = 0; c < NC_; ++c) {
    float4 v = p[(size_t)c * (B_ * H_ * D_ / 4) + i];
    a.x += v.x; a.y += v.y; a.z += v.z; a.w += v.w;
  }
  ((float4*)y)[i] = a;
}

// K6a: ppart[c][b][p] = sum_{d in chunk c} y[b,h(p),d] * w_kv[d][P+p]
__global__ void __launch_bounds__(256) k_pooled_part(const float* __restrict__ y,
                                                     const float* __restrict__ w_kv,
                                                     float* __restrict__ ppart) {
  int c = blockIdx.x;   // NPC_=64 chunks of PCH_=16 rows
  int d0 = c * PCH_;
  int t = threadIdx.x;  // owns columns 4t..4t+3 of P
  int h = t >> 5;       // head of those columns
  __shared__ float sy[PCH_][B_ * H_];  // sy[dd][b*8+h]
  for (int i = t; i < PCH_ * B_ * H_; i += 256) {
    int dd = i >> 6, bh = i & 63;
    sy[dd][bh] = y[((size_t)bh << 10) + d0 + dd];
  }
  __syncthreads();
  float4 acc[B_];
#pragma unroll
  for (int b = 0; b < B_; ++b) acc[b] = make_float4(0.f, 0.f, 0.f, 0.f);
#pragma unroll
  for (int dd = 0; dd < PCH_; ++dd) {
    float4 wv = ((const float4*)(w_kv + (size_t)(d0 + dd) * (2 * P_) + P_))[t];
#pragma unroll
    for (int b = 0; b < B_; ++b) {
      float yv = sy[dd][b * H_ + h];
      acc[b].x += yv * wv.x; acc[b].y += yv * wv.y;
      acc[b].z += yv * wv.z; acc[b].w += yv * wv.w;
    }
  }
#pragma unroll
  for (int b = 0; b < B_; ++b)
    ((float4*)(ppart + (((size_t)c * B_ + b) << 10)))[t] = acc[b];
}

// K6b: pooled[b][p] = sum_c ppart[c][b][p]
__global__ void __launch_bounds__(256) k_reduce_pooled(const float* __restrict__ ppart,
                                                       float* __restrict__ pooled) {
  int i = blockIdx.x * 256 + threadIdx.x;  // 2048 float4s over (b,p)
  int b = i >> 8, p4 = i & 255;
  float4 a = make_float4(0.f, 0.f, 0.f, 0.f);
  const float4* p = (const float4*)ppart;
#pragma unroll 8
  for (int c = 0; c < NPC_; ++c) {
    float4 v = p[((c * B_ + b) << 8) + p4];
    a.x += v.x; a.y += v.y; a.z += v.z; a.w += v.w;
  }
  ((float4*)pooled)[i] = a;
}

// K7: out[b][o] = sum_p pooled[b][p] * w_out_w[o][p] + w_out_b[o]  (wave per o)
__global__ void __launch_bounds__(256) k_out(const float* __restrict__ pooled,
                                             const float* __restrict__ w_out_w,
                                             const float* __restrict__ w_out_b,
                                             float* __restrict__ out) {
  int wid = threadIdx.x >> 6, lane = threadIdx.x & 63;
  int o = blockIdx.x * 4 + wid;  // 1024 outputs
  const float4* wr = (const float4*)(w_out_w + (size_t)o * P_);
  float4 wv[4];
#pragma unroll
  for (int j = 0; j < 4; ++j) wv[j] = wr[lane + 64 * j];
  float res[B_];
#pragma unroll
  for (int b = 0; b < B_; ++b) {
    const float4* pb = (const float4*)(pooled + b * P_);
    float a = 0.f;
#pragma unroll
    for (int j = 0; j < 4; ++j) {
      float4 pv = pb[lane + 64 * j];
      a += wv[j].x * pv.x + wv[j].y * pv.y + wv[j].z * pv.z + wv[j].w * pv.w;
    }
#pragma unroll
    for (int off = 32; off; off >>= 1) a += __shfl_down(a, off, 64);
    res[b] = a;
  }
  if (lane == 0) {
    float bias = w_out_b[o];
#pragma unroll
    for (int b = 0; b < B_; ++b) out[b * OUT_ + o] = res[b] + bias;
  }
}

extern "C" void kernel_launch(void* const* d_in, const int* in_sizes, int n_in,
                              void* d_out, int out_size, void* d_ws, size_t ws_size,
                              hipStream_t stream) {
  const float* x       = (const float*)d_in[0];  // (B,T,D)
  const float* w_kv    = (const float*)d_in[1];  // (D, 2P)
  const float* query   = (const float*)d_in[2];  // (H, HD)
  const float* w_out_w = (const float*)d_in[3];  // (OUT, P)
  const float* w_out_b = (const float*)d_in[4];  // (OUT,)
  float* out = (float*)d_out;                    // (B, OUT)

  float* ws = (float*)d_ws;
  float* qp      = ws;                                    // H*D     = 8192
  float* lA      = qp + H_ * D_;                          // B*H*T   = 262144
  float* lB      = lA + B_ * H_ * T_;                     // B*H*T   = 262144
  float* partial = lB + B_ * H_ * T_;                     // NC*B*H*D = 4194304
  float* y       = partial + (size_t)NC_ * B_ * H_ * D_;  // B*H*D   = 65536
  float* pooled  = y + B_ * H_ * D_;                      // B*P     = 8192
  // ppart reuses the yacc partial buffer (free after k_reduce_y): NPC*B*P = 524288 floats
  float* ppart   = partial;

  k_qproj<<<D_, 256, 0, stream>>>(w_kv, query, qp);
  k_logits<<<2 * (B_ * T_ / TRL_), 256, 0, stream>>>(x, qp, lA, lB);
  k_yacc<<<dim3(NC_, B_), 256, 0, stream>>>(x, lA, lB, partial);
  k_reduce_y<<<(B_ * H_ * D_ / 4) / 256, 256, 0, stream>>>(partial, y);
  k_pooled_part<<<NPC_, 256, 0, stream>>>(y, w_kv, ppart);
  k_reduce_pooled<<<(B_ * P_ / 4) / 256, 256, 0, stream>>>(ppart, pooled);
  k_out<<<OUT_ / 4, 256, 0, stream>>>(pooled, w_out_w, w_out_b, out);
}